// Round 8
// baseline (235.389 us; speedup 1.0000x reference)
//
#include <hip/hip_runtime.h>
#include <cstdint>

#define DEV static __device__ __forceinline__

typedef __bf16 bf16x8 __attribute__((ext_vector_type(8)));
typedef __bf16 bf16x4 __attribute__((ext_vector_type(4)));
typedef short  s16x4  __attribute__((ext_vector_type(4)));
typedef float  f32x4  __attribute__((ext_vector_type(4)));

DEV unsigned short f32_bf16(float f) {
  union { float f; unsigned u; } v; v.f = f;
  unsigned r = v.u + 0x7FFFu + ((v.u >> 16) & 1u);
  return (unsigned short)(r >> 16);
}

DEV void gload16(const void* g, void* lds) {
  __builtin_amdgcn_global_load_lds((__attribute__((address_space(1))) void*)g,
                                   (__attribute__((address_space(3))) void*)lds,
                                   16, 0, 0);
}

DEV float bcast_lane(float v, int srclane) {
  union { float f; int i; } u; u.f = v;
  u.i = __builtin_amdgcn_ds_bpermute(srclane << 2, u.i);
  return u.f;
}

// 16x16x16 bf16 MFMA: A[m=lane&15][k=quad*4+j], B[k=quad*4+j][n=lane&15],
// C/D col=lane&15 row=quad*4+r. P (from S^T C-layout) feeds A directly.
DEV f32x4 mfma16_bf16(bf16x4 a, bf16x4 b, f32x4 c) {
  union { bf16x4 h; s16x4 s; } ua, ub; ua.h = a; ub.h = b;
#if __has_builtin(__builtin_amdgcn_mfma_f32_16x16x16bf16_1k)
  return __builtin_amdgcn_mfma_f32_16x16x16bf16_1k(ua.s, ub.s, c, 0, 0, 0);
#else
  f32x4 d;
  asm("v_mfma_f32_16x16x16_bf16 %0, %1, %2, %3" : "=v"(d) : "v"(ua.s), "v"(ub.s), "v"(c));
  return d;
#endif
}

// ---------------- fused: cast fp32->bf16 (blocks 0..4095) + mask check (rest) ----------------
__global__ void cast_and_check(const float* __restrict__ x, unsigned short* __restrict__ y,
                               const float* __restrict__ m, int* __restrict__ flag) {
  int bx = blockIdx.x;
  if (bx < 4096) {
    int i = bx * 256 + threadIdx.x;
    float4 v = ((const float4*)x)[i];
    uint2 o;
    o.x = (unsigned)f32_bf16(v.x) | ((unsigned)f32_bf16(v.y) << 16);
    o.y = (unsigned)f32_bf16(v.z) | ((unsigned)f32_bf16(v.w) << 16);
    ((uint2*)y)[i] = o;
  } else {
    size_t i = ((size_t)(bx - 4096) * 256 + threadIdx.x) * 4;
    float4 v = *(const float4*)(m + i);
    if (v.x != 1.0f || v.y != 1.0f || v.z != 1.0f || v.w != 1.0f) atomicOr(flag, 1);
  }
}

// ---------------- fused transpose-cast of both weights: W[K][N] fp32 -> WT[N][K] bf16 ----------------
__global__ void transpose_cast2(const float* __restrict__ W1, unsigned short* __restrict__ WT1,
                                const float* __restrict__ W2, unsigned short* __restrict__ WT2) {
  __shared__ float t[64][65];
  int bx = blockIdx.x;
  const float* W; unsigned short* WT; int N, kb, nb;
  if (bx < 768) { W = W1; WT = WT1; N = 3072; kb = bx & 15; nb = bx >> 4; }
  else { bx -= 768; W = W2; WT = WT2; N = 1024; kb = bx & 15; nb = bx >> 4; }
  const int K = 1024;
  int k0 = kb * 64, n0 = nb * 64;
  int tn = threadIdx.x & 63, tk = threadIdx.x >> 6;
#pragma unroll
  for (int i = 0; i < 64; i += 4)
    t[tk + i][tn] = W[(size_t)(k0 + tk + i) * N + n0 + tn];
  __syncthreads();
  int k2 = (threadIdx.x & 31) * 2, n = threadIdx.x >> 5;
#pragma unroll
  for (int i = 0; i < 64; i += 8) {
    int nn = n + i;
    unsigned o = (unsigned)f32_bf16(t[k2][nn]) | ((unsigned)f32_bf16(t[k2 + 1][nn]) << 16);
    *(unsigned*)&WT[(size_t)(n0 + nn) * K + k0 + k2] = o;
  }
}

// ---------------- GEMM: C[M][N] = A[M][K] * BT[N][K]^T ----------------
// MODE 0: fp32 C. MODE 2: scatter Qb/Kb [b,h,s,d], VTb [b,h,d,s] (TN must be 128).
template <int MODE, int TN>
__global__ void __launch_bounds__(256) gemm_bt(const unsigned short* __restrict__ A,
                                               const unsigned short* __restrict__ BT,
                                               float* __restrict__ Cout,
                                               unsigned short* __restrict__ Qb,
                                               unsigned short* __restrict__ Kb,
                                               unsigned short* __restrict__ VTb,
                                               int M, int N, int K) {
  constexpr int NT = TN / 32;
  __shared__ __align__(16) unsigned short As[128 * 32];
  __shared__ __align__(16) unsigned short Bs[TN * 32];
  const int tid = threadIdx.x, wave = tid >> 6, lane = tid & 63;
  const int l = lane & 15, quad = lane >> 4;
  const int wm = (wave & 1) * 64, wn = (wave >> 1) * (TN >> 1);
  const int bm = blockIdx.x, bn = blockIdx.y;

  const int srowA = wave * 32 + (lane >> 2);
  const int sswzA = ((lane & 3) ^ (srowA & 3)) * 8;
  const int srowB = (TN == 128) ? srowA : (wave * 16 + (lane >> 2));
  const int sswzB = ((lane & 3) ^ (srowB & 3)) * 8;
  const unsigned short* pA = A + (size_t)(bm * 128 + srowA) * K + sswzA;
  const unsigned short* pB = BT + (size_t)(bn * TN + srowB) * K + sswzB;
  unsigned short* ldsA0 = &As[(wave * 32) * 32];
  unsigned short* ldsA1 = &As[(wave * 32 + 16) * 32];
  unsigned short* ldsB0 = &Bs[((TN == 128 ? wave * 32 : wave * 16)) * 32];
  unsigned short* ldsB1 = &Bs[(wave * 32 + 16) * 32];  // TN==128 only

  f32x4 acc[4][NT];
#pragma unroll
  for (int i = 0; i < 4; i++)
#pragma unroll
    for (int j = 0; j < NT; j++) { f32x4 z = {0.f, 0.f, 0.f, 0.f}; acc[i][j] = z; }

  for (int kt = 0; kt < K; kt += 32) {
    __syncthreads();
    gload16(pA, ldsA0);
    gload16(pA + (size_t)16 * K, ldsA1);
    gload16(pB, ldsB0);
    if (TN == 128) gload16(pB + (size_t)16 * K, ldsB1);
    pA += 32; pB += 32;
    __syncthreads();
    bf16x8 af[4], bv[NT];
#pragma unroll
    for (int mt = 0; mt < 4; mt++) {
      int r = wm + mt * 16 + l;
      af[mt] = *(const bf16x8*)&As[r * 32 + ((quad ^ (r & 3)) * 8)];
    }
#pragma unroll
    for (int nt = 0; nt < NT; nt++) {
      int r = wn + nt * 16 + l;
      bv[nt] = *(const bf16x8*)&Bs[r * 32 + ((quad ^ (r & 3)) * 8)];
    }
#pragma unroll
    for (int mt = 0; mt < 4; mt++)
#pragma unroll
      for (int nt = 0; nt < NT; nt++)
        acc[mt][nt] = __builtin_amdgcn_mfma_f32_16x16x32_bf16(af[mt], bv[nt], acc[mt][nt], 0, 0, 0);
  }

#pragma unroll
  for (int nt = 0; nt < NT; nt++) {
    const int col = bn * TN + wn + nt * 16 + l;
#pragma unroll
    for (int mt = 0; mt < 4; mt++) {
      const int row0 = bm * 128 + wm + mt * 16 + quad * 4;
      if (MODE == 0) {
#pragma unroll
        for (int r = 0; r < 4; r++)
          Cout[(size_t)(row0 + r) * N + col] = acc[mt][nt][r];
      } else {
        const int bb = row0 >> 11, s = row0 & 2047;
        if (col < 2048) {
          unsigned short* dst = (col < 1024) ? Qb : Kb;
          const int c = col & 1023;
          const size_t off = ((size_t)(bb * 16 + (c >> 6)) * 2048 + s) * 64 + (c & 63);
#pragma unroll
          for (int r = 0; r < 4; r++)
            dst[off + (size_t)r * 64] = f32_bf16(acc[mt][nt][r]);
        } else {
          const int c = col - 2048;
          const size_t off = ((size_t)(bb * 16 + (c >> 6)) * 64 + (c & 63)) * 2048 + s;
          bf16x4 pk;
#pragma unroll
          for (int r = 0; r < 4; r++) pk[r] = (__bf16)acc[mt][nt][r];
          *(bf16x4*)&VTb[off] = pk;
        }
      }
    }
  }
}

// ---------------- flash attention: 512-thread blocks, two 4-wave groups split K-halves ----------------
// grid 512 = 16 q-tiles(128) x 32 (b,h). Group g runs over k in [g*1024,(g+1)*1024).
// R8: fused per-ntk inner loop — (2 ds_read K -> 2 QK-MFMA -> bias+exp+cvt -> 4 ds_read V
// -> 8 PV-MFMA) per 16-k slice, instead of three monolithic bursts. Homogeneous pipe mix
// lets co-resident waves overlap DS/VALU/MFMA instead of colliding burst-on-burst.
__global__ void __launch_bounds__(512, 2) attn(const unsigned short* __restrict__ Qb,
                                               const unsigned short* __restrict__ Kb,
                                               const unsigned short* __restrict__ VTb,
                                               const float* __restrict__ mask,
                                               const float* __restrict__ emb,
                                               const int* __restrict__ mflag,
                                               unsigned short* __restrict__ ctx) {
  __shared__ __align__(16) unsigned short KV[2][16384];  // per group: K(128x64) + V^T(64x128)
  __shared__ float biasLUT[512];
  __shared__ float Lbuf[128];

  const float LOG2E = 1.4426950408889634f;
  const float c1 = 0.125f * LOG2E;
  const float C2 = 10000.0f * LOG2E;
  const int tid = threadIdx.x, wave = tid >> 6, lane = tid & 63;
  const int g = wave >> 2, gw = wave & 3;
  const int l = lane & 15, quad = lane >> 4;
  const int qt = blockIdx.x & 15, bh = blockIdx.x >> 4;
  const int b = bh >> 4, h = bh & 15;
  const int q0 = qt * 128;

  {
    int rel = tid - 256;
    int rp = rel < 0 ? -rel : rel;
    int off = rp < 8 ? rp
                     : 8 + (rp >= 12) + (rp >= 16) + (rp >= 23) + (rp >= 32) +
                           (rp >= 46) + (rp >= 64) + (rp >= 91);
    int bucket = (rel > 0 ? 16 : 0) + off;
    biasLUT[tid] = emb[bucket * 16 + h] * LOG2E;
  }
  const float satL = emb[15 * 16 + h] * LOG2E;
  const float satH = emb[31 * 16 + h] * LOG2E;
  const int masked = *mflag;

  const unsigned short* qbg = Qb  + ((size_t)(b * 16 + h) * 2048 + q0) * 64;
  const unsigned short* kbg = Kb  + (size_t)(b * 16 + h) * 2048 * 64;
  const unsigned short* vtb = VTb + (size_t)(b * 16 + h) * 64 * 2048;
  const float* mbase = mask + (size_t)b * 2048 * 2048;

  const int rw8 = lane >> 3, c8 = lane & 7;
  const int rw16 = lane >> 4, c16 = lane & 15;

  // ---- stage Q (128x64) once into KV[0], all 8 waves read their fragments ----
  if (wave < 4) {
#pragma unroll
    for (int j = 0; j < 4; j++) {
      int row = wave * 32 + j * 8 + rw8;
      gload16(qbg + (size_t)row * 64 + ((c8 ^ (row & 7)) * 8), &KV[0][(wave * 32 + j * 8) * 64]);
    }
  }
  __syncthreads();
  bf16x8 qf[2][2];
#pragma unroll
  for (int mtq = 0; mtq < 2; mtq++)
#pragma unroll
    for (int ks = 0; ks < 2; ks++) {
      int row = gw * 32 + mtq * 16 + l;
      qf[mtq][ks] = *(const bf16x8*)&KV[0][row * 64 + (((ks * 4 + quad) ^ (row & 7)) * 8)];
    }

  float lr[2] = {0.f, 0.f};
  f32x4 Oa[2][4];
#pragma unroll
  for (int mt = 0; mt < 2; mt++)
#pragma unroll
    for (int dt = 0; dt < 4; dt++) { f32x4 z = {0.f, 0.f, 0.f, 0.f}; Oa[mt][dt] = z; }

  unsigned short* Ks  = &KV[g][0];
  unsigned short* VTs = &KV[g][8192];

  for (int t = 0; t < 8; t++) {
    const int k0 = (g * 8 + t) * 128;
    __syncthreads();  // prior frag reads (and iter0: Q frag reads) done
    // ---- stage K tile (128x64), swizzled ----
#pragma unroll
    for (int j = 0; j < 4; j++) {
      int row = gw * 32 + j * 8 + rw8;
      gload16(kbg + (size_t)(k0 + row) * 64 + ((c8 ^ (row & 7)) * 8),
              &Ks[(gw * 32 + j * 8) * 64]);
    }
    // ---- stage V^T tile (64d x 128k), swizzled ----
#pragma unroll
    for (int j = 0; j < 4; j++) {
      int drow = gw * 16 + j * 4 + rw16;
      gload16(vtb + (size_t)drow * 2048 + k0 + ((c16 ^ (drow & 7)) * 8),
              &VTs[(gw * 16 + j * 4) * 128]);
    }
    __syncthreads();

    // ---- fused per-ntk: QK -> softmax -> PV ----
    const int d0 = k0 - q0;
    const bool sat = (d0 >= 256) || (d0 <= -256);
    const float bias_u = d0 > 0 ? satH : satL;
    const int ibase = 256 + d0 + quad * 4 - gw * 32 - l;

#pragma unroll
    for (int ntk = 0; ntk < 8; ntk++) {
      int row = ntk * 16 + l;
      bf16x8 kf0 = *(const bf16x8*)&Ks[row * 64 + ((quad ^ (row & 7)) * 8)];
      bf16x8 kf1 = *(const bf16x8*)&Ks[row * 64 + (((4 + quad) ^ (row & 7)) * 8)];
      bf16x4 vf[4];
#pragma unroll
      for (int dt = 0; dt < 4; dt++) {
        int drow = dt * 16 + l;
        int ch = (ntk * 2 + (quad >> 1)) ^ (l & 7);
        vf[dt] = *(const bf16x4*)&VTs[drow * 128 + ch * 8 + (quad & 1) * 4];
      }
      bf16x4 pa[2];
#pragma unroll
      for (int mtq = 0; mtq < 2; mtq++) {
        f32x4 s = {0.f, 0.f, 0.f, 0.f};
        s = __builtin_amdgcn_mfma_f32_16x16x32_bf16(kf0, qf[mtq][0], s, 0, 0, 0);
        s = __builtin_amdgcn_mfma_f32_16x16x32_bf16(kf1, qf[mtq][1], s, 0, 0, 0);

        const int ib = ibase - mtq * 16 + ntk * 16;
        if (!masked) {
          if (sat) {
#pragma unroll
            for (int r = 0; r < 4; r++) s[r] = fmaf(s[r], c1, bias_u);
          } else {
#pragma unroll
            for (int r = 0; r < 4; r++) s[r] = fmaf(s[r], c1, biasLUT[ib + r]);
          }
        } else {
          const int qg = q0 + gw * 32 + mtq * 16 + l;
          const int kg = k0 + ntk * 16 + quad * 4;
          float4 mv4 = *(const float4*)&mbase[(size_t)qg * 2048 + kg];
#pragma unroll
          for (int r = 0; r < 4; r++) {
            float mv = r == 0 ? mv4.x : (r == 1 ? mv4.y : (r == 2 ? mv4.z : mv4.w));
            float bias = sat ? bias_u : biasLUT[ib + r];
            s[r] = fmaf(s[r], mv * c1, fmaf(mv, C2, bias - C2));
          }
        }
        bf16x4 pk;
        float ls = 0.f;
#pragma unroll
        for (int r = 0; r < 4; r++) {
          float p = __builtin_amdgcn_exp2f(s[r]);  // softmax shift-invariance: no max needed
          ls += p;
          pk[r] = (__bf16)p;
        }
        lr[mtq] += ls;
        pa[mtq] = pk;
      }
#pragma unroll
      for (int mtq = 0; mtq < 2; mtq++)
#pragma unroll
        for (int dt = 0; dt < 4; dt++)
          Oa[mtq][dt] = mfma16_bf16(pa[mtq], vf[dt], Oa[mtq][dt]);
    }
  }

  // ---- cross-quad l reduce (both groups) ----
#pragma unroll
  for (int mtq = 0; mtq < 2; mtq++) {
    float v = lr[mtq];
    v += __shfl_xor(v, 16);
    v += __shfl_xor(v, 32);
    lr[mtq] = v;
  }

  // ---- combine group partials: group1 -> LDS (reuses its K/V buffer), group0 adds ----
  float* Obuf = (float*)&KV[1][0];  // 64 d-rows x 128 q (chunk-swizzled), 32 KB
  __syncthreads();  // all loop LDS reads done
  if (g == 1) {
#pragma unroll
    for (int mt = 0; mt < 2; mt++) {
#pragma unroll
      for (int dt = 0; dt < 4; dt++) {
        const int qc = gw * 8 + mt * 4 + quad;
        *(f32x4*)&Obuf[(dt * 16 + l) * 128 + ((qc ^ (l & 7)) * 4)] = Oa[mt][dt];
      }
      if (quad == 0) Lbuf[gw * 32 + mt * 16 + l] = lr[mt];
    }
  }
  __syncthreads();
  if (g == 0) {
    float inv[2];
#pragma unroll
    for (int mt = 0; mt < 2; mt++)
      inv[mt] = 1.0f / (lr[mt] + Lbuf[gw * 32 + mt * 16 + l]);
#pragma unroll
    for (int mt = 0; mt < 2; mt++)
#pragma unroll
      for (int dt = 0; dt < 4; dt++) {
        const int qc = gw * 8 + mt * 4 + quad;
        f32x4 o = Oa[mt][dt];
        o += *(const f32x4*)&Obuf[(dt * 16 + l) * 128 + ((qc ^ (l & 7)) * 4)];
#pragma unroll
        for (int r = 0; r < 4; r++) {
          float i_bc = bcast_lane(inv[mt], quad * 4 + r);
          const int qg = q0 + gw * 32 + mt * 16 + quad * 4 + r;
          ctx[(size_t)(b * 2048 + qg) * 1024 + h * 64 + dt * 16 + l] =
              f32_bf16(o[r] * i_bc);
        }
      }
  }
}

// ---------------- launch ----------------
extern "C" void kernel_launch(void* const* d_in, const int* in_sizes, int n_in,
                              void* d_out, int out_size, void* d_ws, size_t ws_size,
                              hipStream_t stream) {
  const float* hs   = (const float*)d_in[0];
  const float* mask = (const float*)d_in[1];
  const float* wqkv = (const float*)d_in[2];
  const float* wo   = (const float*)d_in[3];
  const float* emb  = (const float*)d_in[4];
  float* out = (float*)d_out;

  char* ws = (char*)d_ws;
  unsigned short* hB  = (unsigned short*)(ws);               //  8 MB (alias ctx)
  unsigned short* ctx = (unsigned short*)(ws);               //  alias
  unsigned short* wqT = (unsigned short*)(ws + 8388608);     //  6 MB
  unsigned short* woT = (unsigned short*)(ws + 14680064);    //  2 MB
  unsigned short* Qb  = (unsigned short*)(ws + 16777216);    //  8 MB  [b,h,s,d]
  unsigned short* Kb  = (unsigned short*)(ws + 25165824);    //  8 MB  [b,h,s,d]
  unsigned short* VTb = (unsigned short*)(ws + 33554432);    //  8 MB  [b,h,d,s]
  int* mflag          = (int*)(ws + 41943040);
  if (ws_size < 41943044) return;

  hipMemsetAsync(mflag, 0, 4, stream);
  cast_and_check<<<12288, 256, 0, stream>>>(hs, hB, mask, mflag);
  transpose_cast2<<<1024, 256, 0, stream>>>(wqkv, wqT, wo, woT);
  gemm_bt<2, 128><<<dim3(32, 24), 256, 0, stream>>>(hB, wqT, nullptr, Qb, Kb, VTb, 4096, 3072, 1024);
  attn<<<512, 512, 0, stream>>>(Qb, Kb, VTb, mask, emb, mflag, ctx);
  gemm_bt<0, 64><<<dim3(32, 16), 256, 0, stream>>>(ctx, woT, out, nullptr, nullptr, nullptr, 4096, 1024, 1024);
}

// Round 9
// 226.788 us; speedup vs baseline: 1.0379x; 1.0379x over previous
//
#include <hip/hip_runtime.h>
#include <cstdint>

#define DEV static __device__ __forceinline__

typedef __bf16 bf16x8 __attribute__((ext_vector_type(8)));
typedef __bf16 bf16x4 __attribute__((ext_vector_type(4)));
typedef short  s16x4  __attribute__((ext_vector_type(4)));
typedef float  f32x4  __attribute__((ext_vector_type(4)));

#define C1L 0.18033688f  /* 0.125 * log2(e) */

DEV unsigned short f32_bf16(float f) {
  union { float f; unsigned u; } v; v.f = f;
  unsigned r = v.u + 0x7FFFu + ((v.u >> 16) & 1u);
  return (unsigned short)(r >> 16);
}

DEV void gload16(const void* g, void* lds) {
  __builtin_amdgcn_global_load_lds((__attribute__((address_space(1))) void*)g,
                                   (__attribute__((address_space(3))) void*)lds,
                                   16, 0, 0);
}

DEV float bcast_lane(float v, int srclane) {
  union { float f; int i; } u; u.f = v;
  u.i = __builtin_amdgcn_ds_bpermute(srclane << 2, u.i);
  return u.f;
}

// 16x16x16 bf16 MFMA: A[m=lane&15][k=quad*4+j] — P from S^T C-layout feeds A directly.
DEV f32x4 mfma16_bf16(bf16x4 a, bf16x4 b, f32x4 c) {
  union { bf16x4 h; s16x4 s; } ua, ub; ua.h = a; ub.h = b;
#if __has_builtin(__builtin_amdgcn_mfma_f32_16x16x16bf16_1k)
  return __builtin_amdgcn_mfma_f32_16x16x16bf16_1k(ua.s, ub.s, c, 0, 0, 0);
#else
  f32x4 d;
  asm("v_mfma_f32_16x16x16_bf16 %0, %1, %2, %3" : "=v"(d) : "v"(ua.s), "v"(ub.s), "v"(c));
  return d;
#endif
}

// ---------------- fused: cast fp32->bf16 (blocks 0..4095) + mask check (rest) ----------------
__global__ void cast_and_check(const float* __restrict__ x, unsigned short* __restrict__ y,
                               const float* __restrict__ m, int* __restrict__ flag) {
  int bx = blockIdx.x;
  if (bx < 4096) {
    int i = bx * 256 + threadIdx.x;
    float4 v = ((const float4*)x)[i];
    uint2 o;
    o.x = (unsigned)f32_bf16(v.x) | ((unsigned)f32_bf16(v.y) << 16);
    o.y = (unsigned)f32_bf16(v.z) | ((unsigned)f32_bf16(v.w) << 16);
    ((uint2*)y)[i] = o;
  } else {
    size_t i = ((size_t)(bx - 4096) * 256 + threadIdx.x) * 4;
    float4 v = *(const float4*)(m + i);
    if (v.x != 1.0f || v.y != 1.0f || v.z != 1.0f || v.w != 1.0f) atomicOr(flag, 1);
  }
}

// ---------------- fused transpose-cast of both weights ----------------
__global__ void transpose_cast2(const float* __restrict__ W1, unsigned short* __restrict__ WT1,
                                const float* __restrict__ W2, unsigned short* __restrict__ WT2) {
  __shared__ float t[64][65];
  int bx = blockIdx.x;
  const float* W; unsigned short* WT; int N, kb, nb;
  if (bx < 768) { W = W1; WT = WT1; N = 3072; kb = bx & 15; nb = bx >> 4; }
  else { bx -= 768; W = W2; WT = WT2; N = 1024; kb = bx & 15; nb = bx >> 4; }
  const int K = 1024;
  int k0 = kb * 64, n0 = nb * 64;
  int tn = threadIdx.x & 63, tk = threadIdx.x >> 6;
#pragma unroll
  for (int i = 0; i < 64; i += 4)
    t[tk + i][tn] = W[(size_t)(k0 + tk + i) * N + n0 + tn];
  __syncthreads();
  int k2 = (threadIdx.x & 31) * 2, n = threadIdx.x >> 5;
#pragma unroll
  for (int i = 0; i < 64; i += 8) {
    int nn = n + i;
    unsigned o = (unsigned)f32_bf16(t[k2][nn]) | ((unsigned)f32_bf16(t[k2 + 1][nn]) << 16);
    *(unsigned*)&WT[(size_t)(n0 + nn) * K + k0 + k2] = o;
  }
}

// ---------------- GEMM: C[M][N] = A[M][K] * BT[N][K]^T ----------------
// MODE 0: fp32 C. MODE 2: scatter Qb/Kb [b,h,s,d], VTb [b,h,d,s]; Q pre-scaled by C1L.
template <int MODE, int TN>
__global__ void __launch_bounds__(256) gemm_bt(const unsigned short* __restrict__ A,
                                               const unsigned short* __restrict__ BT,
                                               float* __restrict__ Cout,
                                               unsigned short* __restrict__ Qb,
                                               unsigned short* __restrict__ Kb,
                                               unsigned short* __restrict__ VTb,
                                               int M, int N, int K) {
  constexpr int NT = TN / 32;
  __shared__ __align__(16) unsigned short As[128 * 32];
  __shared__ __align__(16) unsigned short Bs[TN * 32];
  const int tid = threadIdx.x, wave = tid >> 6, lane = tid & 63;
  const int l = lane & 15, quad = lane >> 4;
  const int wm = (wave & 1) * 64, wn = (wave >> 1) * (TN >> 1);
  const int bm = blockIdx.x, bn = blockIdx.y;

  const int srowA = wave * 32 + (lane >> 2);
  const int sswzA = ((lane & 3) ^ (srowA & 3)) * 8;
  const int srowB = (TN == 128) ? srowA : (wave * 16 + (lane >> 2));
  const int sswzB = ((lane & 3) ^ (srowB & 3)) * 8;
  const unsigned short* pA = A + (size_t)(bm * 128 + srowA) * K + sswzA;
  const unsigned short* pB = BT + (size_t)(bn * TN + srowB) * K + sswzB;
  unsigned short* ldsA0 = &As[(wave * 32) * 32];
  unsigned short* ldsA1 = &As[(wave * 32 + 16) * 32];
  unsigned short* ldsB0 = &Bs[((TN == 128 ? wave * 32 : wave * 16)) * 32];
  unsigned short* ldsB1 = &Bs[(wave * 32 + 16) * 32];  // TN==128 only

  f32x4 acc[4][NT];
#pragma unroll
  for (int i = 0; i < 4; i++)
#pragma unroll
    for (int j = 0; j < NT; j++) { f32x4 z = {0.f, 0.f, 0.f, 0.f}; acc[i][j] = z; }

  for (int kt = 0; kt < K; kt += 32) {
    __syncthreads();
    gload16(pA, ldsA0);
    gload16(pA + (size_t)16 * K, ldsA1);
    gload16(pB, ldsB0);
    if (TN == 128) gload16(pB + (size_t)16 * K, ldsB1);
    pA += 32; pB += 32;
    __syncthreads();
    bf16x8 af[4], bv[NT];
#pragma unroll
    for (int mt = 0; mt < 4; mt++) {
      int r = wm + mt * 16 + l;
      af[mt] = *(const bf16x8*)&As[r * 32 + ((quad ^ (r & 3)) * 8)];
    }
#pragma unroll
    for (int nt = 0; nt < NT; nt++) {
      int r = wn + nt * 16 + l;
      bv[nt] = *(const bf16x8*)&Bs[r * 32 + ((quad ^ (r & 3)) * 8)];
    }
#pragma unroll
    for (int mt = 0; mt < 4; mt++)
#pragma unroll
      for (int nt = 0; nt < NT; nt++)
        acc[mt][nt] = __builtin_amdgcn_mfma_f32_16x16x32_bf16(af[mt], bv[nt], acc[mt][nt], 0, 0, 0);
  }

#pragma unroll
  for (int nt = 0; nt < NT; nt++) {
    const int col = bn * TN + wn + nt * 16 + l;
#pragma unroll
    for (int mt = 0; mt < 4; mt++) {
      const int row0 = bm * 128 + wm + mt * 16 + quad * 4;
      if (MODE == 0) {
#pragma unroll
        for (int r = 0; r < 4; r++)
          Cout[(size_t)(row0 + r) * N + col] = acc[mt][nt][r];
      } else {
        const int bb = row0 >> 11, s = row0 & 2047;
        if (col < 2048) {
          unsigned short* dst = (col < 1024) ? Qb : Kb;
          const float sc = (col < 1024) ? C1L : 1.0f;  // Q pre-scaled for exp2-domain attn
          const int c = col & 1023;
          const size_t off = ((size_t)(bb * 16 + (c >> 6)) * 2048 + s) * 64 + (c & 63);
#pragma unroll
          for (int r = 0; r < 4; r++)
            dst[off + (size_t)r * 64] = f32_bf16(acc[mt][nt][r] * sc);
        } else {
          const int c = col - 2048;
          const size_t off = ((size_t)(bb * 16 + (c >> 6)) * 64 + (c & 63)) * 2048 + s;
          bf16x4 pk;
#pragma unroll
          for (int r = 0; r < 4; r++) pk[r] = (__bf16)acc[mt][nt][r];
          *(bf16x4*)&VTb[off] = pk;
        }
      }
    }
  }
}

// ---------------- flash attention: 2q x 2k wave split ----------------
// grid 512 = 16 q-tiles(128) x 32 (b,h); block 256 = 4 waves.
// Wave (qi,kj): q-rows [qi*64, qi*64+64) x k-cols [kj*64, kj*64+64) of each 128-k tile.
// Halves per-wave K/V LDS re-reads vs q-only split (each wave reads 16 KB/iter not 32).
// Q pre-scaled by C1L in gemm1; bias enters as the QK MFMA C-initializer (sat sub-blocks
// |rel|>=106-15: scalar broadcast; else 512-entry LUT). No-max softmax (shift-invariant);
// kj partials combined once via LDS reuse of the K/V buffer.
__global__ void __launch_bounds__(256, 2) attn(const unsigned short* __restrict__ Qb,
                                               const unsigned short* __restrict__ Kb,
                                               const unsigned short* __restrict__ VTb,
                                               const float* __restrict__ mask,
                                               const float* __restrict__ emb,
                                               const int* __restrict__ mflag,
                                               unsigned short* __restrict__ ctx) {
  __shared__ __align__(16) unsigned short KVbuf[16384];  // Ks[128x64] + VTs[64x128]; Obuf after loop
  __shared__ float biasLUT[512];
  __shared__ float Lbuf[128];
  unsigned short* Ks  = KVbuf;
  unsigned short* VTs = KVbuf + 8192;

  const float LOG2E = 1.4426950408889634f;
  const float C2 = 10000.0f * LOG2E;
  const int tid = threadIdx.x, wave = tid >> 6, lane = tid & 63;
  const int qi = wave >> 1, kj = wave & 1;
  const int l = lane & 15, quad = lane >> 4;
  const int qt = blockIdx.x & 15, bh = blockIdx.x >> 4;
  const int b = bh >> 4, h = bh & 15;
  const int q0 = qt * 128;

  for (int i = tid; i < 512; i += 256) {
    int rel = i - 256;
    int rp = rel < 0 ? -rel : rel;
    int off = rp < 8 ? rp
                     : 8 + (rp >= 12) + (rp >= 16) + (rp >= 23) + (rp >= 32) +
                           (rp >= 46) + (rp >= 64) + (rp >= 91);
    int bucket = (rel > 0 ? 16 : 0) + off;
    biasLUT[i] = emb[bucket * 16 + h] * LOG2E;
  }
  const float satL = emb[15 * 16 + h] * LOG2E;
  const float satH = emb[31 * 16 + h] * LOG2E;
  const int masked = *mflag;

  const unsigned short* qbg = Qb  + ((size_t)(b * 16 + h) * 2048 + q0) * 64;
  const unsigned short* kbg = Kb  + (size_t)(b * 16 + h) * 2048 * 64;
  const unsigned short* vtb = VTb + (size_t)(b * 16 + h) * 64 * 2048;
  const float* mbase = mask + (size_t)b * 2048 * 2048;

  const int rw8 = lane >> 3, c8 = lane & 7;
  const int rw16 = lane >> 4, c16 = lane & 15;

  // ---- stage Q (128x64) into Ks region; each wave reads its 64 q-rows ----
#pragma unroll
  for (int j = 0; j < 4; j++) {
    int row = wave * 32 + j * 8 + rw8;
    gload16(qbg + (size_t)row * 64 + ((c8 ^ (row & 7)) * 8), &Ks[(wave * 32 + j * 8) * 64]);
  }
  __syncthreads();
  bf16x8 qf[4][2];
#pragma unroll
  for (int mtq = 0; mtq < 4; mtq++)
#pragma unroll
    for (int ks = 0; ks < 2; ks++) {
      int row = qi * 64 + mtq * 16 + l;
      qf[mtq][ks] = *(const bf16x8*)&Ks[row * 64 + (((ks * 4 + quad) ^ (row & 7)) * 8)];
    }

  float lr[4] = {0.f, 0.f, 0.f, 0.f};
  f32x4 Oa[4][4];
#pragma unroll
  for (int mt = 0; mt < 4; mt++)
#pragma unroll
    for (int dt = 0; dt < 4; dt++) { f32x4 z = {0.f, 0.f, 0.f, 0.f}; Oa[mt][dt] = z; }

  for (int t = 0; t < 16; t++) {
    const int k0 = t * 128;
    __syncthreads();  // prior frag reads done (iter0: Q frag reads done)
#pragma unroll
    for (int j = 0; j < 4; j++) {
      int row = wave * 32 + j * 8 + rw8;
      gload16(kbg + (size_t)(k0 + row) * 64 + ((c8 ^ (row & 7)) * 8),
              &Ks[(wave * 32 + j * 8) * 64]);
    }
#pragma unroll
    for (int j = 0; j < 4; j++) {
      int drow = wave * 16 + j * 4 + rw16;
      gload16(vtb + (size_t)drow * 2048 + k0 + ((c16 ^ (drow & 7)) * 8),
              &VTs[(wave * 16 + j * 4) * 128]);
    }
    __syncthreads();

    // ---- QK burst: S^T = K Q'^T with bias as C-init (Q' pre-scaled) ----
    bf16x4 pa[4][4];
#pragma unroll
    for (int ntk = 0; ntk < 4; ntk++) {
      const int row = kj * 64 + ntk * 16 + l;
      bf16x8 kf0 = *(const bf16x8*)&Ks[row * 64 + ((quad ^ (row & 7)) * 8)];
      bf16x8 kf1 = *(const bf16x8*)&Ks[row * 64 + (((4 + quad) ^ (row & 7)) * 8)];
#pragma unroll
      for (int mtq = 0; mtq < 4; mtq++) {
        const int base16 = (k0 + kj * 64 + ntk * 16) - (q0 + qi * 64 + mtq * 16);
        const bool sat = (base16 >= 106) || (base16 <= -106);
        const float bias_u = base16 > 0 ? satH : satL;
        const int ib = 256 + base16 + quad * 4 - l;
        f32x4 s;
        if (masked) {
          f32x4 z = {0.f, 0.f, 0.f, 0.f}; s = z;
        } else if (sat) {
          s[0] = bias_u; s[1] = bias_u; s[2] = bias_u; s[3] = bias_u;
        } else {
#pragma unroll
          for (int r = 0; r < 4; r++) s[r] = biasLUT[ib + r];
        }
        s = __builtin_amdgcn_mfma_f32_16x16x32_bf16(kf0, qf[mtq][0], s, 0, 0, 0);
        s = __builtin_amdgcn_mfma_f32_16x16x32_bf16(kf1, qf[mtq][1], s, 0, 0, 0);

        if (masked) {
          const int qg = q0 + qi * 64 + mtq * 16 + l;
          const int kg = k0 + kj * 64 + ntk * 16 + quad * 4;
          float4 mv4 = *(const float4*)&mbase[(size_t)qg * 2048 + kg];
#pragma unroll
          for (int r = 0; r < 4; r++) {
            float mv = r == 0 ? mv4.x : (r == 1 ? mv4.y : (r == 2 ? mv4.z : mv4.w));
            float bias = sat ? bias_u : biasLUT[ib + r];
            s[r] = fmaf(s[r], mv, fmaf(mv, C2, bias - C2));
          }
        }
        bf16x4 pk;
        float ls = 0.f;
#pragma unroll
        for (int r = 0; r < 4; r++) {
          float p = __builtin_amdgcn_exp2f(s[r]);
          ls += p;
          pk[r] = (__bf16)p;
        }
        lr[mtq] += ls;
        pa[mtq][ntk] = pk;
      }
    }

    // ---- PV burst on this wave's 64 k-cols ----
#pragma unroll
    for (int ntk = 0; ntk < 4; ntk++) {
      bf16x4 vf[4];
#pragma unroll
      for (int dt = 0; dt < 4; dt++) {
        int drow = dt * 16 + l;
        int ck = kj * 8 + ntk * 2 + (quad >> 1);
        vf[dt] = *(const bf16x4*)&VTs[drow * 128 + ((ck ^ (l & 7)) * 8) + (quad & 1) * 4];
      }
#pragma unroll
      for (int mtq = 0; mtq < 4; mtq++)
#pragma unroll
        for (int dt = 0; dt < 4; dt++)
          Oa[mtq][dt] = mfma16_bf16(pa[mtq][ntk], vf[dt], Oa[mtq][dt]);
    }
  }

  // ---- cross-quad l reduce ----
#pragma unroll
  for (int mtq = 0; mtq < 4; mtq++) {
    float v = lr[mtq];
    v += __shfl_xor(v, 16);
    v += __shfl_xor(v, 32);
    lr[mtq] = v;
  }

  // ---- combine kj partials via LDS (reuse K/V buffer as 128x64 fp32 Obuf) ----
  float* Obuf = (float*)KVbuf;
  __syncthreads();  // all loop LDS reads done
  if (kj == 1) {
#pragma unroll
    for (int mtq = 0; mtq < 4; mtq++) {
#pragma unroll
      for (int dt = 0; dt < 4; dt++)
#pragma unroll
        for (int r = 0; r < 4; r++) {
          const int q = qi * 64 + mtq * 16 + quad * 4 + r;
          Obuf[q * 64 + dt * 16 + l] = Oa[mtq][dt][r];
        }
      if (quad == 0) Lbuf[qi * 64 + mtq * 16 + l] = lr[mtq];
    }
  }
  __syncthreads();
  if (kj == 0) {
    float inv[4];
#pragma unroll
    for (int mtq = 0; mtq < 4; mtq++)
      inv[mtq] = 1.0f / (lr[mtq] + Lbuf[qi * 64 + mtq * 16 + l]);
#pragma unroll
    for (int mtq = 0; mtq < 4; mtq++)
#pragma unroll
      for (int dt = 0; dt < 4; dt++) {
#pragma unroll
        for (int r = 0; r < 4; r++) {
          const int q = qi * 64 + mtq * 16 + quad * 4 + r;
          float o = Oa[mtq][dt][r] + Obuf[q * 64 + dt * 16 + l];
          float i_bc = bcast_lane(inv[mtq], quad * 4 + r);
          const int qg = q0 + q;
          ctx[(size_t)(b * 2048 + qg) * 1024 + h * 64 + dt * 16 + l] = f32_bf16(o * i_bc);
        }
      }
  }
}

// ---------------- launch ----------------
extern "C" void kernel_launch(void* const* d_in, const int* in_sizes, int n_in,
                              void* d_out, int out_size, void* d_ws, size_t ws_size,
                              hipStream_t stream) {
  const float* hs   = (const float*)d_in[0];
  const float* mask = (const float*)d_in[1];
  const float* wqkv = (const float*)d_in[2];
  const float* wo   = (const float*)d_in[3];
  const float* emb  = (const float*)d_in[4];
  float* out = (float*)d_out;

  char* ws = (char*)d_ws;
  unsigned short* hB  = (unsigned short*)(ws);               //  8 MB (alias ctx)
  unsigned short* ctx = (unsigned short*)(ws);               //  alias
  unsigned short* wqT = (unsigned short*)(ws + 8388608);     //  6 MB
  unsigned short* woT = (unsigned short*)(ws + 14680064);    //  2 MB
  unsigned short* Qb  = (unsigned short*)(ws + 16777216);    //  8 MB  [b,h,s,d] (pre-scaled)
  unsigned short* Kb  = (unsigned short*)(ws + 25165824);    //  8 MB  [b,h,s,d]
  unsigned short* VTb = (unsigned short*)(ws + 33554432);    //  8 MB  [b,h,d,s]
  int* mflag          = (int*)(ws + 41943040);
  if (ws_size < 41943044) return;

  hipMemsetAsync(mflag, 0, 4, stream);
  cast_and_check<<<12288, 256, 0, stream>>>(hs, hB, mask, mflag);
  transpose_cast2<<<1024, 256, 0, stream>>>(wqkv, wqT, wo, woT);
  gemm_bt<2, 128><<<dim3(32, 24), 256, 0, stream>>>(hB, wqT, nullptr, Qb, Kb, VTb, 4096, 3072, 1024);
  attn<<<512, 256, 0, stream>>>(Qb, Kb, VTb, mask, emb, mflag, ctx);
  gemm_bt<0, 64><<<dim3(32, 16), 256, 0, stream>>>(ctx, woT, out, nullptr, nullptr, nullptr, 4096, 1024, 1024);
}